// Round 1
// baseline (369.550 us; speedup 1.0000x reference)
//
#include <hip/hip_runtime.h>
#include <math.h>
#include <float.h>

#define N 4096
#define D 256
#define NLAB 64

static constexpr float INV_TEMP = 1.0f / 0.07f;
static constexpr float W_ORGAN = 2.0f;  // ORGAN_W (exact_pos weight)
static constexpr float W_FINE  = 4.0f;  // FINE_W  (organ_pos * sim weight)

#define BM 64
#define BN 64
#define KC 64
#define NQ 8
#define JC (N / NQ)    // 512 cols per block
#define NJT (JC / BN)  // 8 tiles
#define NKC (D / KC)   // 4 k-chunks
#define PAD 4          // keeps LDS rows 16B-aligned for ds_read_b128

// ---------------------------------------------------------------- pass 1: row max
__global__ __launch_bounds__(256)
void kmax(const float* __restrict__ F, float* __restrict__ Mpart)
{
    __shared__ float As[KC][BM + PAD];
    __shared__ float Bs[KC][BN + PAD];

    const int p  = blockIdx.x / NQ;
    const int q  = blockIdx.x % NQ;
    const int i0 = p * BM;
    const int j0 = q * JC;
    const int t  = threadIdx.x;
    const int tx = t & 15, ty = t >> 4;

    float rmax[4] = {-FLT_MAX, -FLT_MAX, -FLT_MAX, -FLT_MAX};

    for (int jt = 0; jt < NJT; ++jt) {
        const int jb = j0 + jt * BN;
        float acc[4][4] = {};
        for (int kc = 0; kc < NKC; ++kc) {
            __syncthreads();
            // stage A (transposed to k-major) and B
            #pragma unroll
            for (int r = 0; r < 4; ++r) {
                const int f  = t + 256 * r;
                const int m  = f >> 4;
                const int kq = f & 15;
                float4 va = *(const float4*)&F[(size_t)(i0 + m) * D + kc * KC + kq * 4];
                As[kq * 4 + 0][m] = va.x; As[kq * 4 + 1][m] = va.y;
                As[kq * 4 + 2][m] = va.z; As[kq * 4 + 3][m] = va.w;
                float4 vb = *(const float4*)&F[(size_t)(jb + m) * D + kc * KC + kq * 4];
                Bs[kq * 4 + 0][m] = vb.x; Bs[kq * 4 + 1][m] = vb.y;
                Bs[kq * 4 + 2][m] = vb.z; Bs[kq * 4 + 3][m] = vb.w;
            }
            __syncthreads();
            #pragma unroll 16
            for (int k = 0; k < KC; ++k) {
                float4 a = *(const float4*)&As[k][ty * 4];
                float4 b = *(const float4*)&Bs[k][tx * 4];
                const float av[4] = {a.x, a.y, a.z, a.w};
                const float bv[4] = {b.x, b.y, b.z, b.w};
                #pragma unroll
                for (int r = 0; r < 4; ++r)
                    #pragma unroll
                    for (int c = 0; c < 4; ++c)
                        acc[r][c] = fmaf(av[r], bv[c], acc[r][c]);
            }
        }
        #pragma unroll
        for (int r = 0; r < 4; ++r) {
            const int gi = i0 + ty * 4 + r;
            #pragma unroll
            for (int c = 0; c < 4; ++c) {
                const int gj = jb + tx * 4 + c;
                float s = acc[r][c] * INV_TEMP;
                if (gi == gj) s = -1e9f;
                rmax[r] = fmaxf(rmax[r], s);
            }
        }
    }
    // reduce across tx (16-lane groups within the wave)
    #pragma unroll
    for (int r = 0; r < 4; ++r) {
        float v = rmax[r];
        for (int o = 1; o < 16; o <<= 1)
            v = fmaxf(v, __shfl_xor(v, o));
        if (tx == 0) Mpart[(size_t)q * N + i0 + ty * 4 + r] = v;
    }
}

// ---------------------------------------------------------------- reduce partial max
__global__ __launch_bounds__(256)
void kredmax(const float* __restrict__ Mpart, float* __restrict__ M)
{
    const int i = blockIdx.x * 256 + threadIdx.x;
    float v = -FLT_MAX;
    #pragma unroll
    for (int q = 0; q < NQ; ++q) v = fmaxf(v, Mpart[(size_t)q * N + i]);
    M[i] = v;
}

// ---------------------------------------------------------------- pass 2: weighted sums
__global__ __launch_bounds__(256)
void ksum(const float* __restrict__ F, const int* __restrict__ labels,
          const float* __restrict__ simtab, const float* __restrict__ M,
          float* __restrict__ DenP, float* __restrict__ WlgP,
          float* __restrict__ WsmP, float* __restrict__ CntP)
{
    __shared__ float As[KC][BM + PAD];
    __shared__ float Bs[KC][BN + PAD];
    __shared__ float sim_s[NLAB][NLAB];
    __shared__ int   labB_s[BN];

    const int p  = blockIdx.x / NQ;
    const int q  = blockIdx.x % NQ;
    const int i0 = p * BM;
    const int j0 = q * JC;
    const int t  = threadIdx.x;
    const int tx = t & 15, ty = t >> 4;

    for (int idx = t; idx < NLAB * NLAB; idx += 256)
        sim_s[idx >> 6][idx & 63] = simtab[idx];

    int   labA[4];
    float Mreg[4];
    #pragma unroll
    for (int r = 0; r < 4; ++r) {
        labA[r] = labels[i0 + ty * 4 + r];
        Mreg[r] = M[i0 + ty * 4 + r];
    }
    float den[4] = {}, wlg[4] = {}, wsm[4] = {}, cnt[4] = {};

    for (int jt = 0; jt < NJT; ++jt) {
        const int jb = j0 + jt * BN;
        __syncthreads();                    // protect labB_s vs previous epilogue
        if (t < BN) labB_s[t] = labels[jb + t];
        float acc[4][4] = {};
        for (int kc = 0; kc < NKC; ++kc) {
            __syncthreads();
            #pragma unroll
            for (int r = 0; r < 4; ++r) {
                const int f  = t + 256 * r;
                const int m  = f >> 4;
                const int kq = f & 15;
                float4 va = *(const float4*)&F[(size_t)(i0 + m) * D + kc * KC + kq * 4];
                As[kq * 4 + 0][m] = va.x; As[kq * 4 + 1][m] = va.y;
                As[kq * 4 + 2][m] = va.z; As[kq * 4 + 3][m] = va.w;
                float4 vb = *(const float4*)&F[(size_t)(jb + m) * D + kc * KC + kq * 4];
                Bs[kq * 4 + 0][m] = vb.x; Bs[kq * 4 + 1][m] = vb.y;
                Bs[kq * 4 + 2][m] = vb.z; Bs[kq * 4 + 3][m] = vb.w;
            }
            __syncthreads();
            #pragma unroll 16
            for (int k = 0; k < KC; ++k) {
                float4 a = *(const float4*)&As[k][ty * 4];
                float4 b = *(const float4*)&Bs[k][tx * 4];
                const float av[4] = {a.x, a.y, a.z, a.w};
                const float bv[4] = {b.x, b.y, b.z, b.w};
                #pragma unroll
                for (int r = 0; r < 4; ++r)
                    #pragma unroll
                    for (int c = 0; c < 4; ++c)
                        acc[r][c] = fmaf(av[r], bv[c], acc[r][c]);
            }
        }
        #pragma unroll
        for (int r = 0; r < 4; ++r) {
            const int gi = i0 + ty * 4 + r;
            #pragma unroll
            for (int c = 0; c < 4; ++c) {
                const int gj = jb + tx * 4 + c;
                float s = acc[r][c] * INV_TEMP;
                const bool ne = (gi != gj);
                if (!ne) s = -1e9f;
                const float logit = fminf(fmaxf(s - Mreg[r], -50.0f), 50.0f);
                den[r] += __expf(logit);
                const float sim = sim_s[labA[r]][labB_s[tx * 4 + c]];
                const bool organ = ne && (sim > 0.0f) && (sim < 1.0f);
                const bool exact = ne && (sim == 1.0f);
                const float w = organ ? sim * W_FINE : (exact ? W_ORGAN : 0.0f);
                wlg[r] += w * logit;
                wsm[r] += w;
                cnt[r] += (organ || exact) ? 1.0f : 0.0f;
            }
        }
    }
    #pragma unroll
    for (int r = 0; r < 4; ++r) {
        float v0 = den[r], v1 = wlg[r], v2 = wsm[r], v3 = cnt[r];
        for (int o = 1; o < 16; o <<= 1) {
            v0 += __shfl_xor(v0, o);
            v1 += __shfl_xor(v1, o);
            v2 += __shfl_xor(v2, o);
            v3 += __shfl_xor(v3, o);
        }
        if (tx == 0) {
            const size_t idx = (size_t)q * N + i0 + ty * 4 + r;
            DenP[idx] = v0; WlgP[idx] = v1; WsmP[idx] = v2; CntP[idx] = v3;
        }
    }
}

// ---------------------------------------------------------------- finalize
__global__ __launch_bounds__(256)
void kfinal(const float* __restrict__ DenP, const float* __restrict__ WlgP,
            const float* __restrict__ WsmP, const float* __restrict__ CntP,
            float* __restrict__ out)
{
    const int t = threadIdx.x;
    float lsum = 0.f, np = 0.f;
    for (int i = t; i < N; i += 256) {
        float den = 0.f, wlg = 0.f, wsm = 0.f, cnt = 0.f;
        #pragma unroll
        for (int q = 0; q < NQ; ++q) {
            den += DenP[(size_t)q * N + i];
            wlg += WlgP[(size_t)q * N + i];
            wsm += WsmP[(size_t)q * N + i];
            cnt += CntP[(size_t)q * N + i];
        }
        const float logden = logf(den + 1e-8f);
        const float mlp = (wlg - logden * wsm) / fmaxf(wsm, 1e-8f);
        if (cnt > 0.f) { lsum += mlp; np += 1.f; }
    }
    __shared__ float s1[4], s2[4];
    for (int o = 32; o; o >>= 1) {
        lsum += __shfl_down(lsum, o);
        np   += __shfl_down(np, o);
    }
    const int wid = t >> 6;
    if ((t & 63) == 0) { s1[wid] = lsum; s2[wid] = np; }
    __syncthreads();
    if (t == 0) {
        const float L = s1[0] + s1[1] + s1[2] + s1[3];
        const float P = s2[0] + s2[1] + s2[2] + s2[3];
        out[0] = -L / fmaxf(P, 1.0f);
    }
}

// ---------------------------------------------------------------- launch
extern "C" void kernel_launch(void* const* d_in, const int* in_sizes, int n_in,
                              void* d_out, int out_size, void* d_ws, size_t ws_size,
                              hipStream_t stream)
{
    const float* F      = (const float*)d_in[0];
    const int*   labels = (const int*)d_in[1];
    const float* simtab = (const float*)d_in[2];
    float* out = (float*)d_out;
    float* ws  = (float*)d_ws;

    float* Mpart = ws;                       // NQ*N
    float* M     = Mpart + (size_t)NQ * N;   // N
    float* DenP  = M + N;                    // NQ*N
    float* WlgP  = DenP + (size_t)NQ * N;    // NQ*N
    float* WsmP  = WlgP + (size_t)NQ * N;    // NQ*N
    float* CntP  = WsmP + (size_t)NQ * N;    // NQ*N

    dim3 grid((N / BM) * NQ);                // 64 * 8 = 512
    kmax<<<grid, 256, 0, stream>>>(F, Mpart);
    kredmax<<<N / 256, 256, 0, stream>>>(Mpart, M);
    ksum<<<grid, 256, 0, stream>>>(F, labels, simtab, M, DenP, WlgP, WsmP, CntP);
    kfinal<<<1, 256, 0, stream>>>(DenP, WlgP, WsmP, CntP, out);
}

// Round 3
// 130.315 us; speedup vs baseline: 2.8358x; 2.8358x over previous
//
#include <hip/hip_runtime.h>
#include <math.h>
#include <float.h>

#define N 4096
#define D 256
#define NLAB 64
#define NT 32            // 128-wide row/col tiles
#define NC 64            // column-chunk partial slices (NT * 2 waves)

static constexpr float INV_TEMP = 1.0f / 0.07f;
static constexpr float W_ORGAN = 2.0f;
static constexpr float W_FINE  = 4.0f;

typedef __bf16 bf16x8 __attribute__((ext_vector_type(8)));
typedef float  f32x4  __attribute__((ext_vector_type(4)));
typedef unsigned short u16;

typedef __attribute__((address_space(3))) char lds_char;
typedef __attribute__((address_space(1))) const char gbl_char;

// ---------------------------------------------------------------- bf16 split helpers
__device__ __forceinline__ u16 f2bf_rn(float x) {
    unsigned u = __float_as_uint(x);
    unsigned r = (u + 0x7fffu + ((u >> 16) & 1u)) >> 16;
    return (u16)r;
}
__device__ __forceinline__ float bf2f(u16 b) { return __uint_as_float(((unsigned)b) << 16); }

__global__ __launch_bounds__(256)
void ksplit(const float* __restrict__ F, u16* __restrict__ Fhi, u16* __restrict__ Flo)
{
    const int idx = blockIdx.x * 256 + threadIdx.x;    // one float4 each
    float4 v = ((const float4*)F)[idx];
    ushort4 h, l;
    {
        h.x = f2bf_rn(v.x); l.x = f2bf_rn(v.x - bf2f(h.x));
        h.y = f2bf_rn(v.y); l.y = f2bf_rn(v.y - bf2f(h.y));
        h.z = f2bf_rn(v.z); l.z = f2bf_rn(v.z - bf2f(h.z));
        h.w = f2bf_rn(v.w); l.w = f2bf_rn(v.w - bf2f(h.w));
    }
    ((ushort4*)Fhi)[idx] = h;
    ((ushort4*)Flo)[idx] = l;
}

// ---------------------------------------------------------------- staging: global -> LDS
// LDS tile: [row 0..127][4 slots of 16B]; physical slot p holds logical slot p^(row&3).
__device__ __forceinline__ void stage_chunk(const u16* __restrict__ Fhi, const u16* __restrict__ Flo,
                                            u16* sAh, u16* sAl, u16* sBh, u16* sBl,
                                            int i0, int j0, int kc, int t)
{
    const int w = t >> 6, lane = t & 63;
    #pragma unroll
    for (int i = 0; i < 2; ++i) {
        const int slotbase = w * 128 + i * 64;         // wave-uniform
        const int slot = slotbase + lane;
        const int row  = slot >> 2;
        const int k16  = (slot & 3) ^ (row & 3);       // inverse-swizzled source slot
        const int ldsb = slotbase * 16;                // HW adds lane*16
        const size_t ga = (size_t)(i0 + row) * D + kc * 32 + k16 * 8;
        const size_t gb = (size_t)(j0 + row) * D + kc * 32 + k16 * 8;
        __builtin_amdgcn_global_load_lds((gbl_char*)(Fhi + ga), (lds_char*)((char*)sAh + ldsb), 16, 0, 0);
        __builtin_amdgcn_global_load_lds((gbl_char*)(Flo + ga), (lds_char*)((char*)sAl + ldsb), 16, 0, 0);
        __builtin_amdgcn_global_load_lds((gbl_char*)(Fhi + gb), (lds_char*)((char*)sBh + ldsb), 16, 0, 0);
        __builtin_amdgcn_global_load_lds((gbl_char*)(Flo + gb), (lds_char*)((char*)sBl + ldsb), 16, 0, 0);
    }
}

// ---------------------------------------------------------------- shared GEMM body
__device__ __forceinline__ void gemm_body(const u16* __restrict__ Fhi, const u16* __restrict__ Flo,
                                          u16* sAh, u16* sAl, u16* sBh, u16* sBl,
                                          int i0, int j0, int t, f32x4 acc[4][4])
{
    const int lane = t & 63, lr = lane & 15, lk = lane >> 4;
    const int wv = t >> 6, wr = wv >> 1, wc = wv & 1;

    int aoff[4], boff[4];
    #pragma unroll
    for (int m = 0; m < 4; ++m) {
        const int rowa = wr * 64 + m * 16 + lr;
        aoff[m] = rowa * 64 + ((lk ^ (rowa & 3)) << 4);
        const int rowb = wc * 64 + m * 16 + lr;
        boff[m] = rowb * 64 + ((lk ^ (rowb & 3)) << 4);
    }
    const f32x4 z = {0.f, 0.f, 0.f, 0.f};
    #pragma unroll
    for (int m = 0; m < 4; ++m)
        #pragma unroll
        for (int n = 0; n < 4; ++n) acc[m][n] = z;

    for (int kc = 0; kc < D / 32; ++kc) {
        __syncthreads();
        stage_chunk(Fhi, Flo, sAh, sAl, sBh, sBl, i0, j0, kc, t);
        __syncthreads();
        bf16x8 ah[4], al[4], bh[4], bl[4];
        #pragma unroll
        for (int m = 0; m < 4; ++m) {
            ah[m] = *(const bf16x8*)((const char*)sAh + aoff[m]);
            al[m] = *(const bf16x8*)((const char*)sAl + aoff[m]);
            bh[m] = *(const bf16x8*)((const char*)sBh + boff[m]);
            bl[m] = *(const bf16x8*)((const char*)sBl + boff[m]);
        }
        #pragma unroll
        for (int m = 0; m < 4; ++m)
            #pragma unroll
            for (int n = 0; n < 4; ++n) {
                acc[m][n] = __builtin_amdgcn_mfma_f32_16x16x32_bf16(ah[m], bh[n], acc[m][n], 0, 0, 0);
                acc[m][n] = __builtin_amdgcn_mfma_f32_16x16x32_bf16(ah[m], bl[n], acc[m][n], 0, 0, 0);
                acc[m][n] = __builtin_amdgcn_mfma_f32_16x16x32_bf16(al[m], bh[n], acc[m][n], 0, 0, 0);
            }
    }
}

// ---------------------------------------------------------------- pass 1: row max
__global__ __launch_bounds__(256)
void kgemm_max(const u16* __restrict__ Fhi, const u16* __restrict__ Flo, float* __restrict__ Mpart)
{
    __shared__ u16 sAh[128 * 32], sAl[128 * 32], sBh[128 * 32], sBl[128 * 32];
    const int t = threadIdx.x;
    const int p = blockIdx.x >> 5, q = blockIdx.x & 31;
    const int i0 = p * 128, j0 = q * 128;

    f32x4 acc[4][4];
    gemm_body(Fhi, Flo, sAh, sAl, sBh, sBl, i0, j0, t, acc);

    const int lane = t & 63, lr = lane & 15, lk = lane >> 4;
    const int wv = t >> 6, wr = wv >> 1, wc = wv & 1;
    const int qq = q * 2 + wc;                 // per-column-wave partial slice
    #pragma unroll
    for (int m = 0; m < 4; ++m)
        #pragma unroll
        for (int r = 0; r < 4; ++r) {
            const int gi = i0 + wr * 64 + m * 16 + lk * 4 + r;
            float v = -FLT_MAX;
            #pragma unroll
            for (int n = 0; n < 4; ++n) {
                const int gj = j0 + wc * 64 + n * 16 + lr;
                float s = acc[m][n][r] * INV_TEMP;
                if (gi == gj) s = -1e9f;
                v = fmaxf(v, s);
            }
            v = fmaxf(v, __shfl_xor(v, 1));
            v = fmaxf(v, __shfl_xor(v, 2));
            v = fmaxf(v, __shfl_xor(v, 4));
            v = fmaxf(v, __shfl_xor(v, 8));
            if (lr == 0) Mpart[(size_t)qq * N + gi] = v;
        }
}

// ---------------------------------------------------------------- reduce max
__global__ __launch_bounds__(256)
void kredmax(const float* __restrict__ Mpart, float* __restrict__ M)
{
    const int i = blockIdx.x * 256 + threadIdx.x;
    float v = -FLT_MAX;
    #pragma unroll
    for (int q = 0; q < NC; ++q) v = fmaxf(v, Mpart[(size_t)q * N + i]);
    M[i] = v;
}

// ---------------------------------------------------------------- pass 2: weighted sums
__global__ __launch_bounds__(256)
void kgemm_sum(const u16* __restrict__ Fhi, const u16* __restrict__ Flo,
               const int* __restrict__ labels, const float* __restrict__ simtab,
               const float* __restrict__ M,
               float* __restrict__ DenP, float* __restrict__ WlgP,
               float* __restrict__ WsmP, float* __restrict__ CntP)
{
    __shared__ u16 sAh[128 * 32], sAl[128 * 32], sBh[128 * 32], sBl[128 * 32];
    __shared__ float sim_s[NLAB * NLAB];
    __shared__ int labB_s[128];

    const int t = threadIdx.x;
    const int p = blockIdx.x >> 5, q = blockIdx.x & 31;
    const int i0 = p * 128, j0 = q * 128;

    #pragma unroll
    for (int i = 0; i < 4; ++i)
        ((float4*)sim_s)[t + i * 256] = ((const float4*)simtab)[t + i * 256];
    if (t < 128) labB_s[t] = labels[j0 + t];
    // gemm_body's first __syncthreads() covers these stores

    f32x4 acc[4][4];
    gemm_body(Fhi, Flo, sAh, sAl, sBh, sBl, i0, j0, t, acc);

    const int lane = t & 63, lr = lane & 15, lk = lane >> 4;
    const int wv = t >> 6, wr = wv >> 1, wc = wv & 1;
    const int qq = q * 2 + wc;                 // per-column-wave partial slice
    #pragma unroll
    for (int m = 0; m < 4; ++m)
        #pragma unroll
        for (int r = 0; r < 4; ++r) {
            const int gi = i0 + wr * 64 + m * 16 + lk * 4 + r;
            const int labA = labels[gi];
            const float Mw = M[gi];
            float den = 0.f, wlg = 0.f, wsm = 0.f, cnt = 0.f;
            #pragma unroll
            for (int n = 0; n < 4; ++n) {
                const int cl = wc * 64 + n * 16 + lr;
                const int gj = j0 + cl;
                float s = acc[m][n][r] * INV_TEMP;
                const bool ne = (gi != gj);
                if (!ne) s = -1e9f;
                const float logit = fminf(fmaxf(s - Mw, -50.0f), 50.0f);
                den += __expf(logit);
                const float sim = sim_s[labA * NLAB + labB_s[cl]];
                const bool organ = ne && (sim > 0.0f) && (sim < 1.0f);
                const bool exact = ne && (sim == 1.0f);
                const float w = organ ? sim * W_FINE : (exact ? W_ORGAN : 0.0f);
                wlg += w * logit;
                wsm += w;
                cnt += (organ || exact) ? 1.0f : 0.0f;
            }
            #pragma unroll
            for (int o = 1; o < 16; o <<= 1) {
                den += __shfl_xor(den, o);
                wlg += __shfl_xor(wlg, o);
                wsm += __shfl_xor(wsm, o);
                cnt += __shfl_xor(cnt, o);
            }
            if (lr == 0) {
                const size_t idx = (size_t)qq * N + gi;
                DenP[idx] = den; WlgP[idx] = wlg; WsmP[idx] = wsm; CntP[idx] = cnt;
            }
        }
}

// ---------------------------------------------------------------- per-row combine
__global__ __launch_bounds__(256)
void krow(const float* __restrict__ DenP, const float* __restrict__ WlgP,
          const float* __restrict__ WsmP, const float* __restrict__ CntP,
          float* __restrict__ Mlp, float* __restrict__ Hp)
{
    const int i = blockIdx.x * 256 + threadIdx.x;
    float den = 0.f, wlg = 0.f, wsm = 0.f, cnt = 0.f;
    #pragma unroll
    for (int q = 0; q < NC; ++q) {
        den += DenP[(size_t)q * N + i];
        wlg += WlgP[(size_t)q * N + i];
        wsm += WsmP[(size_t)q * N + i];
        cnt += CntP[(size_t)q * N + i];
    }
    const float logden = logf(den + 1e-8f);
    const float mlp = (wlg - logden * wsm) / fmaxf(wsm, 1e-8f);
    Mlp[i] = (cnt > 0.f) ? mlp : 0.f;
    Hp[i]  = (cnt > 0.f) ? 1.f : 0.f;
}

// ---------------------------------------------------------------- final reduce
__global__ __launch_bounds__(256)
void kfinal(const float* __restrict__ Mlp, const float* __restrict__ Hp, float* __restrict__ out)
{
    const int t = threadIdx.x;
    float ls = 0.f, np = 0.f;
    for (int i = t; i < N; i += 256) { ls += Mlp[i]; np += Hp[i]; }
    #pragma unroll
    for (int o = 32; o; o >>= 1) {
        ls += __shfl_down(ls, o);
        np += __shfl_down(np, o);
    }
    __shared__ float s1[4], s2[4];
    const int wid = t >> 6;
    if ((t & 63) == 0) { s1[wid] = ls; s2[wid] = np; }
    __syncthreads();
    if (t == 0) {
        const float L = s1[0] + s1[1] + s1[2] + s1[3];
        const float P = s2[0] + s2[1] + s2[2] + s2[3];
        out[0] = -L / fmaxf(P, 1.0f);
    }
}

// ---------------------------------------------------------------- launch
extern "C" void kernel_launch(void* const* d_in, const int* in_sizes, int n_in,
                              void* d_out, int out_size, void* d_ws, size_t ws_size,
                              hipStream_t stream)
{
    (void)in_sizes; (void)n_in; (void)out_size; (void)ws_size;
    const float* F      = (const float*)d_in[0];
    const int*   labels = (const int*)d_in[1];
    const float* simtab = (const float*)d_in[2];
    float* out = (float*)d_out;

    u16* Fhi = (u16*)d_ws;                        // N*D u16  (2 MB)
    u16* Flo = Fhi + (size_t)N * D;               // 2 MB
    float* Mpart = (float*)(Flo + (size_t)N * D); // NC*N
    float* M     = Mpart + (size_t)NC * N;        // N
    float* DenP  = M + N;                         // NC*N each
    float* WlgP  = DenP + (size_t)NC * N;
    float* WsmP  = WlgP + (size_t)NC * N;
    float* CntP  = WsmP + (size_t)NC * N;
    float* Mlp   = CntP + (size_t)NC * N;         // N
    float* Hp    = Mlp + N;                       // N

    ksplit<<<(N * D) / (256 * 4), 256, 0, stream>>>(F, Fhi, Flo);
    kgemm_max<<<NT * NT, 256, 0, stream>>>(Fhi, Flo, Mpart);
    kredmax<<<N / 256, 256, 0, stream>>>(Mpart, M);
    kgemm_sum<<<NT * NT, 256, 0, stream>>>(Fhi, Flo, labels, simtab, M,
                                           DenP, WlgP, WsmP, CntP);
    krow<<<N / 256, 256, 0, stream>>>(DenP, WlgP, WsmP, CntP, Mlp, Hp);
    kfinal<<<1, 256, 0, stream>>>(Mlp, Hp, out);
}

// Round 4
// 65.012 us; speedup vs baseline: 5.6844x; 2.0045x over previous
//
#include <hip/hip_runtime.h>
#include <math.h>
#include <float.h>

#define N 4096
#define D 256
#define NLAB 64
#define NT 32            // 128-wide row/col tiles
#define NC 64            // column-chunk partial slices (NT * 2 waves)

static constexpr float INV_TEMP = 1.0f / 0.07f;
static constexpr float W_ORGAN = 2.0f;
static constexpr float W_FINE  = 4.0f;

typedef __bf16 bf16x8 __attribute__((ext_vector_type(8)));
typedef float  f32x4  __attribute__((ext_vector_type(4)));
typedef unsigned short u16;

typedef __attribute__((address_space(3))) char lds_char;
typedef __attribute__((address_space(1))) const char gbl_char;

// ---------------------------------------------------------------- bf16 split helpers
__device__ __forceinline__ u16 f2bf_rn(float x) {
    unsigned u = __float_as_uint(x);
    unsigned r = (u + 0x7fffu + ((u >> 16) & 1u)) >> 16;
    return (u16)r;
}
__device__ __forceinline__ float bf2f(u16 b) { return __uint_as_float(((unsigned)b) << 16); }

__global__ __launch_bounds__(256)
void ksplit(const float* __restrict__ F, u16* __restrict__ Fhi, u16* __restrict__ Flo)
{
    const int idx = blockIdx.x * 256 + threadIdx.x;    // one float4 each
    float4 v = ((const float4*)F)[idx];
    ushort4 h, l;
    {
        h.x = f2bf_rn(v.x); l.x = f2bf_rn(v.x - bf2f(h.x));
        h.y = f2bf_rn(v.y); l.y = f2bf_rn(v.y - bf2f(h.y));
        h.z = f2bf_rn(v.z); l.z = f2bf_rn(v.z - bf2f(h.z));
        h.w = f2bf_rn(v.w); l.w = f2bf_rn(v.w - bf2f(h.w));
    }
    ((ushort4*)Fhi)[idx] = h;
    ((ushort4*)Flo)[idx] = l;
}

// ---------------------------------------------------------------- staging: global -> LDS
// LDS tile: [row 0..127][4 slots of 16B]; physical slot p holds logical slot p^(row&3).
__device__ __forceinline__ void stage_chunk(const u16* __restrict__ Fhi, const u16* __restrict__ Flo,
                                            u16* sAh, u16* sAl, u16* sBh, u16* sBl,
                                            int i0, int j0, int kc, int t)
{
    const int w = t >> 6, lane = t & 63;
    #pragma unroll
    for (int i = 0; i < 2; ++i) {
        const int slotbase = w * 128 + i * 64;         // wave-uniform
        const int slot = slotbase + lane;
        const int row  = slot >> 2;
        const int k16  = (slot & 3) ^ (row & 3);       // inverse-swizzled source slot
        const int ldsb = slotbase * 16;                // HW adds lane*16
        const size_t ga = (size_t)(i0 + row) * D + kc * 32 + k16 * 8;
        const size_t gb = (size_t)(j0 + row) * D + kc * 32 + k16 * 8;
        __builtin_amdgcn_global_load_lds((gbl_char*)(Fhi + ga), (lds_char*)((char*)sAh + ldsb), 16, 0, 0);
        __builtin_amdgcn_global_load_lds((gbl_char*)(Flo + ga), (lds_char*)((char*)sAl + ldsb), 16, 0, 0);
        __builtin_amdgcn_global_load_lds((gbl_char*)(Fhi + gb), (lds_char*)((char*)sBh + ldsb), 16, 0, 0);
        __builtin_amdgcn_global_load_lds((gbl_char*)(Flo + gb), (lds_char*)((char*)sBl + ldsb), 16, 0, 0);
    }
}

// ---------------------------------------------------------------- shared GEMM body
__device__ __forceinline__ void gemm_body(const u16* __restrict__ Fhi, const u16* __restrict__ Flo,
                                          u16* sAh, u16* sAl, u16* sBh, u16* sBl,
                                          int i0, int j0, int t, f32x4 acc[4][4])
{
    const int lane = t & 63, lr = lane & 15, lk = lane >> 4;
    const int wv = t >> 6, wr = wv >> 1, wc = wv & 1;

    int aoff[4], boff[4];
    #pragma unroll
    for (int m = 0; m < 4; ++m) {
        const int rowa = wr * 64 + m * 16 + lr;
        aoff[m] = rowa * 64 + ((lk ^ (rowa & 3)) << 4);
        const int rowb = wc * 64 + m * 16 + lr;
        boff[m] = rowb * 64 + ((lk ^ (rowb & 3)) << 4);
    }
    const f32x4 z = {0.f, 0.f, 0.f, 0.f};
    #pragma unroll
    for (int m = 0; m < 4; ++m)
        #pragma unroll
        for (int n = 0; n < 4; ++n) acc[m][n] = z;

    for (int kc = 0; kc < D / 32; ++kc) {
        __syncthreads();
        stage_chunk(Fhi, Flo, sAh, sAl, sBh, sBl, i0, j0, kc, t);
        __syncthreads();
        bf16x8 ah[4], al[4], bh[4], bl[4];
        #pragma unroll
        for (int m = 0; m < 4; ++m) {
            ah[m] = *(const bf16x8*)((const char*)sAh + aoff[m]);
            al[m] = *(const bf16x8*)((const char*)sAl + aoff[m]);
            bh[m] = *(const bf16x8*)((const char*)sBh + boff[m]);
            bl[m] = *(const bf16x8*)((const char*)sBl + boff[m]);
        }
        #pragma unroll
        for (int m = 0; m < 4; ++m)
            #pragma unroll
            for (int n = 0; n < 4; ++n) {
                acc[m][n] = __builtin_amdgcn_mfma_f32_16x16x32_bf16(ah[m], bh[n], acc[m][n], 0, 0, 0);
                acc[m][n] = __builtin_amdgcn_mfma_f32_16x16x32_bf16(ah[m], bl[n], acc[m][n], 0, 0, 0);
                acc[m][n] = __builtin_amdgcn_mfma_f32_16x16x32_bf16(al[m], bh[n], acc[m][n], 0, 0, 0);
            }
    }
}

// ================================================================ NEW PATH
// ---------------------------------------------------------------- GEMM + store S + row-max partials
__global__ __launch_bounds__(256)
void kgemm_store(const u16* __restrict__ Fhi, const u16* __restrict__ Flo,
                 float* __restrict__ S, float* __restrict__ Mpart)
{
    __shared__ u16 sAh[128 * 32], sAl[128 * 32], sBh[128 * 32], sBl[128 * 32];
    const int t = threadIdx.x;
    const int p = blockIdx.x >> 5, q = blockIdx.x & 31;
    const int i0 = p * 128, j0 = q * 128;

    f32x4 acc[4][4];
    gemm_body(Fhi, Flo, sAh, sAl, sBh, sBl, i0, j0, t, acc);

    const int lane = t & 63, lr = lane & 15, lk = lane >> 4;
    const int wv = t >> 6, wr = wv >> 1, wc = wv & 1;
    const int qq = q * 2 + wc;
    #pragma unroll
    for (int m = 0; m < 4; ++m)
        #pragma unroll
        for (int r = 0; r < 4; ++r) {
            const int gi = i0 + wr * 64 + m * 16 + lk * 4 + r;
            float* srow = &S[(size_t)gi * N + j0 + wc * 64];
            float v = -FLT_MAX;
            #pragma unroll
            for (int n = 0; n < 4; ++n) {
                const int gj = j0 + wc * 64 + n * 16 + lr;
                float s = acc[m][n][r] * INV_TEMP;
                if (gi == gj) s = -1e9f;
                srow[n * 16 + lr] = s;
                v = fmaxf(v, s);
            }
            v = fmaxf(v, __shfl_xor(v, 1));
            v = fmaxf(v, __shfl_xor(v, 2));
            v = fmaxf(v, __shfl_xor(v, 4));
            v = fmaxf(v, __shfl_xor(v, 8));
            if (lr == 0) Mpart[(size_t)qq * N + gi] = v;
        }
}

// ---------------------------------------------------------------- reduce max (NC slices)
__global__ __launch_bounds__(256)
void kredmax(const float* __restrict__ Mpart, float* __restrict__ M)
{
    const int i = blockIdx.x * 256 + threadIdx.x;
    float v = -FLT_MAX;
    #pragma unroll
    for (int q = 0; q < NC; ++q) v = fmaxf(v, Mpart[(size_t)q * N + i]);
    M[i] = v;
}

// ---------------------------------------------------------------- elementwise stats over S
__global__ __launch_bounds__(256)
void kstats(const float* __restrict__ S, const int* __restrict__ labels,
            const float* __restrict__ simtab, const float* __restrict__ M,
            float* __restrict__ Mlp, float* __restrict__ Hp)
{
    __shared__ int lab_s[N];                      // 16 KB
    const int t = threadIdx.x;
    for (int i = t; i < N / 4; i += 256)
        ((int4*)lab_s)[i] = ((const int4*)labels)[i];
    __syncthreads();

    const int wv = t >> 6, lane = t & 63;
    const int row = blockIdx.x * 4 + wv;
    const int labA = lab_s[row];
    const float Mi = M[row];

    // lane l holds the weight for labB == l  (cnt>0 <=> w>0 except diagonal)
    const float sim = simtab[labA * NLAB + lane];
    const bool organ = (sim > 0.f) && (sim < 1.f);
    const bool exact = (sim == 1.f);
    const float wlab = organ ? sim * W_FINE : (exact ? W_ORGAN : 0.f);

    float den = 0.f, wlg = 0.f, wsm = 0.f;
    int cnt = 0;
    const float4* Srow = (const float4*)&S[(size_t)row * N];
    #pragma unroll 4
    for (int it = 0; it < N / 256; ++it) {        // 16 iters
        const int j4 = it * 64 + lane;
        const float4 sv = Srow[j4];
        const int4 lb = ((const int4*)lab_s)[j4];
        const float se[4] = {sv.x, sv.y, sv.z, sv.w};
        const int le[4] = {lb.x, lb.y, lb.z, lb.w};
        #pragma unroll
        for (int e = 0; e < 4; ++e) {
            const int j = j4 * 4 + e;
            float w = __shfl(wlab, le[e]);
            if (j == row) w = 0.f;
            const float logit = fminf(fmaxf(se[e] - Mi, -50.f), 50.f);
            den += __expf(logit);
            wlg += w * logit;
            wsm += w;
            cnt += (w > 0.f) ? 1 : 0;
        }
    }
    #pragma unroll
    for (int o = 1; o < 64; o <<= 1) {
        den += __shfl_xor(den, o);
        wlg += __shfl_xor(wlg, o);
        wsm += __shfl_xor(wsm, o);
        cnt += __shfl_xor(cnt, o);
    }
    if (lane == 0) {
        const float logden = logf(den + 1e-8f);
        const float mlp = (wlg - logden * wsm) / fmaxf(wsm, 1e-8f);
        Mlp[row] = (cnt > 0) ? mlp : 0.f;
        Hp[row]  = (cnt > 0) ? 1.f : 0.f;
    }
}

// ================================================================ FALLBACK PATH (verified round-3 kernels)
__global__ __launch_bounds__(256)
void kgemm_max(const u16* __restrict__ Fhi, const u16* __restrict__ Flo, float* __restrict__ Mpart)
{
    __shared__ u16 sAh[128 * 32], sAl[128 * 32], sBh[128 * 32], sBl[128 * 32];
    const int t = threadIdx.x;
    const int p = blockIdx.x >> 5, q = blockIdx.x & 31;
    const int i0 = p * 128, j0 = q * 128;

    f32x4 acc[4][4];
    gemm_body(Fhi, Flo, sAh, sAl, sBh, sBl, i0, j0, t, acc);

    const int lane = t & 63, lr = lane & 15, lk = lane >> 4;
    const int wv = t >> 6, wr = wv >> 1, wc = wv & 1;
    const int qq = q * 2 + wc;
    #pragma unroll
    for (int m = 0; m < 4; ++m)
        #pragma unroll
        for (int r = 0; r < 4; ++r) {
            const int gi = i0 + wr * 64 + m * 16 + lk * 4 + r;
            float v = -FLT_MAX;
            #pragma unroll
            for (int n = 0; n < 4; ++n) {
                const int gj = j0 + wc * 64 + n * 16 + lr;
                float s = acc[m][n][r] * INV_TEMP;
                if (gi == gj) s = -1e9f;
                v = fmaxf(v, s);
            }
            v = fmaxf(v, __shfl_xor(v, 1));
            v = fmaxf(v, __shfl_xor(v, 2));
            v = fmaxf(v, __shfl_xor(v, 4));
            v = fmaxf(v, __shfl_xor(v, 8));
            if (lr == 0) Mpart[(size_t)qq * N + gi] = v;
        }
}

__global__ __launch_bounds__(256)
void kgemm_sum(const u16* __restrict__ Fhi, const u16* __restrict__ Flo,
               const int* __restrict__ labels, const float* __restrict__ simtab,
               const float* __restrict__ M,
               float* __restrict__ DenP, float* __restrict__ WlgP,
               float* __restrict__ WsmP, float* __restrict__ CntP)
{
    __shared__ u16 sAh[128 * 32], sAl[128 * 32], sBh[128 * 32], sBl[128 * 32];
    __shared__ float sim_s[NLAB * NLAB];
    __shared__ int labB_s[128];

    const int t = threadIdx.x;
    const int p = blockIdx.x >> 5, q = blockIdx.x & 31;
    const int i0 = p * 128, j0 = q * 128;

    #pragma unroll
    for (int i = 0; i < 4; ++i)
        ((float4*)sim_s)[t + i * 256] = ((const float4*)simtab)[t + i * 256];
    if (t < 128) labB_s[t] = labels[j0 + t];

    f32x4 acc[4][4];
    gemm_body(Fhi, Flo, sAh, sAl, sBh, sBl, i0, j0, t, acc);

    const int lane = t & 63, lr = lane & 15, lk = lane >> 4;
    const int wv = t >> 6, wr = wv >> 1, wc = wv & 1;
    const int qq = q * 2 + wc;
    #pragma unroll
    for (int m = 0; m < 4; ++m)
        #pragma unroll
        for (int r = 0; r < 4; ++r) {
            const int gi = i0 + wr * 64 + m * 16 + lk * 4 + r;
            const int labA = labels[gi];
            const float Mw = M[gi];
            float den = 0.f, wlg = 0.f, wsm = 0.f, cnt = 0.f;
            #pragma unroll
            for (int n = 0; n < 4; ++n) {
                const int cl = wc * 64 + n * 16 + lr;
                const int gj = j0 + cl;
                float s = acc[m][n][r] * INV_TEMP;
                const bool ne = (gi != gj);
                if (!ne) s = -1e9f;
                const float logit = fminf(fmaxf(s - Mw, -50.0f), 50.0f);
                den += __expf(logit);
                const float sim = sim_s[labA * NLAB + labB_s[cl]];
                const bool organ = ne && (sim > 0.0f) && (sim < 1.0f);
                const bool exact = ne && (sim == 1.0f);
                const float w = organ ? sim * W_FINE : (exact ? W_ORGAN : 0.0f);
                wlg += w * logit;
                wsm += w;
                cnt += (organ || exact) ? 1.0f : 0.0f;
            }
            #pragma unroll
            for (int o = 1; o < 16; o <<= 1) {
                den += __shfl_xor(den, o);
                wlg += __shfl_xor(wlg, o);
                wsm += __shfl_xor(wsm, o);
                cnt += __shfl_xor(cnt, o);
            }
            if (lr == 0) {
                const size_t idx = (size_t)qq * N + gi;
                DenP[idx] = den; WlgP[idx] = wlg; WsmP[idx] = wsm; CntP[idx] = cnt;
            }
        }
}

__global__ __launch_bounds__(256)
void krow(const float* __restrict__ DenP, const float* __restrict__ WlgP,
          const float* __restrict__ WsmP, const float* __restrict__ CntP,
          float* __restrict__ Mlp, float* __restrict__ Hp)
{
    const int i = blockIdx.x * 256 + threadIdx.x;
    float den = 0.f, wlg = 0.f, wsm = 0.f, cnt = 0.f;
    #pragma unroll
    for (int q = 0; q < NC; ++q) {
        den += DenP[(size_t)q * N + i];
        wlg += WlgP[(size_t)q * N + i];
        wsm += WsmP[(size_t)q * N + i];
        cnt += CntP[(size_t)q * N + i];
    }
    const float logden = logf(den + 1e-8f);
    const float mlp = (wlg - logden * wsm) / fmaxf(wsm, 1e-8f);
    Mlp[i] = (cnt > 0.f) ? mlp : 0.f;
    Hp[i]  = (cnt > 0.f) ? 1.f : 0.f;
}

// ---------------------------------------------------------------- final reduce
__global__ __launch_bounds__(256)
void kfinal(const float* __restrict__ Mlp, const float* __restrict__ Hp, float* __restrict__ out)
{
    const int t = threadIdx.x;
    float ls = 0.f, np = 0.f;
    for (int i = t; i < N; i += 256) { ls += Mlp[i]; np += Hp[i]; }
    #pragma unroll
    for (int o = 32; o; o >>= 1) {
        ls += __shfl_down(ls, o);
        np += __shfl_down(np, o);
    }
    __shared__ float s1[4], s2[4];
    const int wid = t >> 6;
    if ((t & 63) == 0) { s1[wid] = ls; s2[wid] = np; }
    __syncthreads();
    if (t == 0) {
        const float L = s1[0] + s1[1] + s1[2] + s1[3];
        const float P = s2[0] + s2[1] + s2[2] + s2[3];
        out[0] = -L / fmaxf(P, 1.0f);
    }
}

// ---------------------------------------------------------------- launch
extern "C" void kernel_launch(void* const* d_in, const int* in_sizes, int n_in,
                              void* d_out, int out_size, void* d_ws, size_t ws_size,
                              hipStream_t stream)
{
    (void)in_sizes; (void)n_in; (void)out_size;
    const float* F      = (const float*)d_in[0];
    const int*   labels = (const int*)d_in[1];
    const float* simtab = (const float*)d_in[2];
    float* out = (float*)d_out;

    u16* Fhi = (u16*)d_ws;                        // N*D u16  (2 MB)
    u16* Flo = Fhi + (size_t)N * D;               // 2 MB
    float* base = (float*)(Flo + (size_t)N * D);

    // new path needs: S (N*N) + Mpart (NC*N) + M + Mlp + Hp  [+ Fhi/Flo]
    const size_t need_new = (size_t)N * D * 2 * 2                       // Fhi+Flo
                          + ((size_t)N * N + (size_t)NC * N + 3 * N) * 4;

    ksplit<<<(N * D) / (256 * 4), 256, 0, stream>>>(F, Fhi, Flo);

    if (ws_size >= need_new) {
        float* S     = base;                          // N*N
        float* Mpart = S + (size_t)N * N;             // NC*N
        float* M     = Mpart + (size_t)NC * N;        // N
        float* Mlp   = M + N;                         // N
        float* Hp    = Mlp + N;                       // N

        kgemm_store<<<NT * NT, 256, 0, stream>>>(Fhi, Flo, S, Mpart);
        kredmax<<<N / 256, 256, 0, stream>>>(Mpart, M);
        kstats<<<N / 4, 256, 0, stream>>>(S, labels, simtab, M, Mlp, Hp);
        kfinal<<<1, 256, 0, stream>>>(Mlp, Hp, out);
    } else {
        float* Mpart = base;                          // NC*N
        float* M     = Mpart + (size_t)NC * N;        // N
        float* DenP  = M + N;
        float* WlgP  = DenP + (size_t)NC * N;
        float* WsmP  = WlgP + (size_t)NC * N;
        float* CntP  = WsmP + (size_t)NC * N;
        float* Mlp   = CntP + (size_t)NC * N;
        float* Hp    = Mlp + N;

        kgemm_max<<<NT * NT, 256, 0, stream>>>(Fhi, Flo, Mpart);
        kredmax<<<N / 256, 256, 0, stream>>>(Mpart, M);
        kgemm_sum<<<NT * NT, 256, 0, stream>>>(Fhi, Flo, labels, simtab, M,
                                               DenP, WlgP, WsmP, CntP);
        krow<<<N / 256, 256, 0, stream>>>(DenP, WlgP, WsmP, CntP, Mlp, Hp);
        kfinal<<<1, 256, 0, stream>>>(Mlp, Hp, out);
    }
}